// Round 9
// baseline (124.532 us; speedup 1.0000x reference)
//
#include <hip/hip_runtime.h>
#include <hip/hip_bf16.h>

typedef __bf16 bf16_t;
typedef __bf16 bf16x4 __attribute__((ext_vector_type(4)));
typedef __bf16 bf16x8 __attribute__((ext_vector_type(8)));
typedef float f32x4 __attribute__((ext_vector_type(4)));

#define M_TOT 8192
#define N_TOT 512
#define K_TOT 2048
#define E_TOT 512
#define NSEG  16          // K segments of 128

__device__ __forceinline__ bf16x8 zero8() {
    bf16x8 v;
#pragma unroll
    for (int i = 0; i < 8; ++i) v[i] = (bf16_t)0.0f;
    return v;
}

// ---------------------------------------------------------------------------
// prep4 (unchanged; correctness-proven r6-r8):
//  blocks [0,256):   LDS-tiled transpose W2[k][n] -> W2t[n][k] bf16
//  blocks [256,288): zb[m][0..8)=cos(theta[q])*cos(x[m,q]) (RX collapse:
//                    |a2|^2-|b2|^2 = cos(theta)*cos(x)); zb[m][8]=1; rest 0
//  blocks [288,296): W1p: permuted W1 rows + bias so h-MFMA C-output lands
//    exactly in main-MFMA A-fragment layout.
//    Row d=(c*2+p)*16+rr holds f = c*32+(rr>>2)*8+p*4+(rr&3).
// ---------------------------------------------------------------------------
__global__ __launch_bounds__(256)
void prep4_kernel(const float* __restrict__ x,
                  const float* __restrict__ theta,
                  const float* __restrict__ W1,
                  const float* __restrict__ b1,
                  const float* __restrict__ W2,
                  bf16_t* __restrict__ W2t,
                  bf16_t* __restrict__ zb,
                  bf16_t* __restrict__ W1p)
{
    const int b = blockIdx.x;
    if (b < 256) {
        __shared__ bf16_t T[64][66];
        const int k0 = (b >> 3) * 64;
        const int n0 = (b & 7) * 64;
        const int kl = threadIdx.x >> 4;
        const int n4 = threadIdx.x & 15;
#pragma unroll
        for (int i = 0; i < 4; ++i) {
            int k = kl + i * 16;
            float4 v = *(const float4*)(W2 + (size_t)(k0 + k) * N_TOT + n0 + n4 * 4);
            T[n4 * 4 + 0][k] = (bf16_t)v.x;
            T[n4 * 4 + 1][k] = (bf16_t)v.y;
            T[n4 * 4 + 2][k] = (bf16_t)v.z;
            T[n4 * 4 + 3][k] = (bf16_t)v.w;
        }
        __syncthreads();
        const int nl = threadIdx.x >> 4;
        const int k4 = threadIdx.x & 15;
#pragma unroll
        for (int i = 0; i < 4; ++i) {
            int n = nl + i * 16;
            bf16x4 v;
            v[0] = T[n][k4 * 4 + 0];
            v[1] = T[n][k4 * 4 + 1];
            v[2] = T[n][k4 * 4 + 2];
            v[3] = T[n][k4 * 4 + 3];
            *(bf16x4*)(W2t + (size_t)(n0 + n) * K_TOT + k0 + k4 * 4) = v;
        }
    } else if (b < 288) {
        const int m = (b - 256) * 256 + threadIdx.x;
        float4 x0 = *(const float4*)(x + (size_t)m * E_TOT);
        float4 x1 = *(const float4*)(x + (size_t)m * E_TOT + 4);
        float xs[8] = {x0.x, x0.y, x0.z, x0.w, x1.x, x1.y, x1.z, x1.w};
        bf16x8 lo;
#pragma unroll
        for (int q = 0; q < 8; ++q)
            lo[q] = (bf16_t)(__builtin_cosf(theta[q]) * __builtin_cosf(xs[q]));
        bf16x8 hi = zero8();
        hi[0] = (bf16_t)1.0f;                  // bias lane at k=8
        *(bf16x8*)(zb + (size_t)m * 16)     = lo;
        *(bf16x8*)(zb + (size_t)m * 16 + 8) = hi;
    } else {
        const int d  = (b - 288) * 256 + threadIdx.x;    // 0..2047
        const int c  = d >> 5;
        const int dd = d & 31;
        const int p  = dd >> 4;
        const int rr = dd & 15;
        const int f  = c * 32 + ((rr >> 2) << 3) + (p << 2) + (rr & 3);
        bf16x8 lo;
#pragma unroll
        for (int q = 0; q < 8; ++q)
            lo[q] = (bf16_t)W1[(size_t)q * K_TOT + f];
        bf16x8 hi = zero8();
        hi[0] = (bf16_t)b1[f];                 // bias at k=8
        *(bf16x8*)(W1p + (size_t)d * 16)     = lo;
        *(bf16x8*)(W1p + (size_t)d * 16 + 8) = hi;
    }
}

// ---------------------------------------------------------------------------
// helpers (256-thread block, block tile 128m x 64n, segment BK=128)
// ---------------------------------------------------------------------------
// B segment: 64n x 128k bf16 = 16KB, as two 64x64 k-tiles.
// Within a k-tile, LDS slot `seg` of row n holds global k-seg g = seg^(n&7).
__device__ __forceinline__ void load_B(const bf16_t* __restrict__ W2t, int n_base,
                                       int k0, int t, uint4 gv[4]) {
#pragma unroll
    for (int j = 0; j < 4; ++j) {
        int s    = t + j * 256;        // 0..1023
        int tile = s >> 9;             // 0..1
        int n    = (s >> 3) & 63;
        int g    = (s & 7) ^ (n & 7);
        gv[j] = *(const uint4*)(W2t + (size_t)(n_base + n) * K_TOT
                                + k0 + tile * 64 + g * 8);
    }
}
__device__ __forceinline__ void write_B(bf16_t* Bb, int t, const uint4 gv[4]) {
#pragma unroll
    for (int j = 0; j < 4; ++j) {
        int s    = t + j * 256;
        int tile = s >> 9;
        int n    = (s >> 3) & 63;
        int seg  = s & 7;
        *(uint4*)(Bb + tile * 4096 + n * 64 + seg * 8) = gv[j];
    }
}

// W1p frags for one FULL 128k segment (2 tiles x 2 chunks x 2 halves = 8).
// Only lanes lq<2 carry real data (k-quads 2,3 of the h-MFMA are zero-pad).
__device__ __forceinline__ void load_wf_seg(const bf16_t* __restrict__ W1p, int k0,
                                            int l15, int lq, bf16x8 wf[8]) {
#pragma unroll
    for (int i = 0; i < 8; ++i) wf[i] = zero8();
    if (lq < 2) {
        const int base = (k0 >> 5) * 2;        // row-group at segment start
#pragma unroll
        for (int i = 0; i < 8; ++i)            // i = tt*4 + c*2 + p
            wf[i] = *(const bf16x8*)(W1p + (size_t)((base + i) * 16 + l15) * 16 + lq * 8);
    }
}

// ---------------------------------------------------------------------------
// one 128k segment, PHASE-SEPARATED for ILP:
//   per 64k tile: (1) 8 hoisted bfr ds_reads, (2) ALL 8 h-MFMAs into hh[]
//   (independent chains, forces wide register liveness), (3) all packs,
//   (4) 16 main MFMAs.  Wave = 32m x 64n (r7 mapping, zero h-duplication).
// ---------------------------------------------------------------------------
__device__ __forceinline__ void compute_seg(const bf16_t* Bb, const bf16x8 wf[8],
                                            const bf16x8 zfrag[2],
                                            int l15, int lq, f32x4 acc[2][4]) {
#pragma unroll
    for (int tt = 0; tt < 2; ++tt) {
        // phase 1: B-frag reads (LDS latency overlaps h-MFMAs below)
        bf16x8 bfr[2][4];
#pragma unroll
        for (int c = 0; c < 2; ++c)
#pragma unroll
            for (int nt = 0; nt < 4; ++nt) {
                int r  = nt * 16 + l15;
                int sg = (c * 4 + lq) ^ (r & 7);
                bfr[c][nt] = *(const bf16x8*)(Bb + tt * 4096 + r * 64 + sg * 8);
            }

        // phase 2: all h-MFMAs (8 independent chains)
        f32x4 hh[2][2][2];
#pragma unroll
        for (int mt = 0; mt < 2; ++mt)
#pragma unroll
            for (int c = 0; c < 2; ++c)
#pragma unroll
                for (int p = 0; p < 2; ++p) {
                    f32x4 zz = (f32x4){0.f, 0.f, 0.f, 0.f};
                    hh[mt][c][p] = __builtin_amdgcn_mfma_f32_16x16x32_bf16(
                        wf[tt * 4 + c * 2 + p], zfrag[mt], zz, 0, 0, 0);
                }

        // phase 3: relu + pack into A-fragments
        bf16x8 af[2][2];
#pragma unroll
        for (int mt = 0; mt < 2; ++mt)
#pragma unroll
            for (int c = 0; c < 2; ++c) {
                bf16x8 a;
#pragma unroll
                for (int r = 0; r < 4; ++r) {
                    a[r]     = (bf16_t)fmaxf(hh[mt][c][0][r], 0.f);
                    a[r + 4] = (bf16_t)fmaxf(hh[mt][c][1][r], 0.f);
                }
                af[mt][c] = a;
            }

        // phase 4: main MFMAs (8 independent acc chains)
#pragma unroll
        for (int c = 0; c < 2; ++c)
#pragma unroll
            for (int mt = 0; mt < 2; ++mt)
#pragma unroll
                for (int nt = 0; nt < 4; ++nt)
                    acc[mt][nt] = __builtin_amdgcn_mfma_f32_16x16x32_bf16(
                        af[mt][c], bfr[c][nt], acc[mt][nt], 0, 0, 0);
    }
}

// ---------------------------------------------------------------------------
// Fused GEMM: out = relu(z@W1+b1) @ W2 + b2
// Block 128m x 64n, 256 thr = 4 waves m-split (wave 32m x 64n, ZERO h-dup).
// Grid 512 = 2 blocks/CU; BK=128 dbuf (2x16KB LDS), ONE barrier/segment.
// W1p frags prefetched a full segment ahead (ping-pong, no copies);
// B staged via VGPRs (precise vmcnt).
// ---------------------------------------------------------------------------
__global__ __launch_bounds__(256, 2)
void ffq_gemm_kernel(const bf16_t* __restrict__ zb,    // [8192][16]
                     const bf16_t* __restrict__ W1p,   // [2048][16] permuted
                     const bf16_t* __restrict__ W2t,   // [512][2048]
                     const float* __restrict__ b2,
                     float* __restrict__ out)          // [8192][512]
{
    __shared__ bf16_t Blds[2][2 * 64 * 64];   // 2 bufs x (two 64x64 k-tiles)

    const int t = threadIdx.x;
    const int w = t >> 6, l = t & 63;
    const int m_base = blockIdx.y * 128;
    const int n_base = blockIdx.x * 64;
    const int wm = w;                          // 4 m-slots of 32
    const int l15 = l & 15, lq = l >> 4;

    // persistent z^T B-frags for this wave's two 16-row m-tiles
    bf16x8 zfrag[2];
#pragma unroll
    for (int mt = 0; mt < 2; ++mt) {
        zfrag[mt] = zero8();
        if (lq < 2)
            zfrag[mt] = *(const bf16x8*)(zb + (size_t)(m_base + wm * 32 + mt * 16 + l15) * 16 + lq * 8);
    }

    f32x4 acc[2][4];
#pragma unroll
    for (int mt = 0; mt < 2; ++mt)
#pragma unroll
        for (int nt = 0; nt < 4; ++nt)
            acc[mt][nt] = (f32x4){0.f, 0.f, 0.f, 0.f};

    uint4 gv[4];
    bf16x8 wfA[8], wfB[8];

    // prologue: segment 0 -> buf0; wf for segment 0
    load_B(W2t, n_base, 0, t, gv);
    load_wf_seg(W1p, 0, l15, lq, wfA);
    write_B(Blds[0], t, gv);

    for (int s = 0; s < NSEG; s += 2) {
        // ---- even segment s (buf0, wfA); prefetch s+1 ----
        __syncthreads();                               // publish buf0
        load_B(W2t, n_base, (s + 1) * 128, t, gv);
        load_wf_seg(W1p, (s + 1) * 128, l15, lq, wfB);
        compute_seg(Blds[0], wfA, zfrag, l15, lq, acc);
        write_B(Blds[1], t, gv);

        // ---- odd segment s+1 (buf1, wfB); prefetch s+2 ----
        __syncthreads();                               // publish buf1
        const bool more = (s + 2 < NSEG);
        if (more) {
            load_B(W2t, n_base, (s + 2) * 128, t, gv);
            load_wf_seg(W1p, (s + 2) * 128, l15, lq, wfA);
        }
        compute_seg(Blds[1], wfB, zfrag, l15, lq, acc);
        if (more) write_B(Blds[0], t, gv);
    }

    // ---- epilogue: C/D layout col=lane&15, row=(lane>>4)*4+r ----
#pragma unroll
    for (int nt = 0; nt < 4; ++nt) {
        int col = n_base + nt * 16 + l15;
        float bias = b2[col];
#pragma unroll
        for (int mt = 0; mt < 2; ++mt) {
#pragma unroll
            for (int r = 0; r < 4; ++r) {
                int row = m_base + wm * 32 + mt * 16 + lq * 4 + r;
                out[(size_t)row * N_TOT + col] = acc[mt][nt][r] + bias;
            }
        }
    }
}

extern "C" void kernel_launch(void* const* d_in, const int* in_sizes, int n_in,
                              void* d_out, int out_size, void* d_ws, size_t ws_size,
                              hipStream_t stream) {
    const float* x     = (const float*)d_in[0];
    const float* theta = (const float*)d_in[1];
    const float* W1    = (const float*)d_in[2];
    const float* b1    = (const float*)d_in[3];
    const float* W2    = (const float*)d_in[4];
    const float* b2    = (const float*)d_in[5];
    float* out = (float*)d_out;

    // ws: [0,2MB) W2t ; [2MB,2.25MB) zb[8192][16] ; then W1p[2048][16]
    const size_t W2T_BYTES = (size_t)N_TOT * K_TOT * sizeof(bf16_t);  // 2 MB
    const size_t ZB_BYTES  = (size_t)M_TOT * 16 * sizeof(bf16_t);     // 256 KB

    bf16_t* W2t = (bf16_t*)d_ws;
    bf16_t* zb  = (bf16_t*)((char*)d_ws + W2T_BYTES);
    bf16_t* W1p = (bf16_t*)((char*)d_ws + W2T_BYTES + ZB_BYTES);

    prep4_kernel<<<296, 256, 0, stream>>>(x, theta, W1, b1, W2, W2t, zb, W1p);

    dim3 grid(N_TOT / 64, M_TOT / 128);   // (8, 64) = 512 blocks, 2/CU
    ffq_gemm_kernel<<<grid, 256, 0, stream>>>(zb, W1p, W2t, b2, out);
}

// Round 10
// 119.879 us; speedup vs baseline: 1.0388x; 1.0388x over previous
//
#include <hip/hip_runtime.h>
#include <hip/hip_bf16.h>

typedef __bf16 bf16_t;
typedef __bf16 bf16x4 __attribute__((ext_vector_type(4)));
typedef __bf16 bf16x8 __attribute__((ext_vector_type(8)));
typedef float f32x4 __attribute__((ext_vector_type(4)));

#define M_TOT 8192
#define N_TOT 512
#define K_TOT 2048
#define E_TOT 512
#define NSEG_HALF 8       // 8 segments of 128k per k-half block

__device__ __forceinline__ bf16x8 zero8() {
    bf16x8 v;
#pragma unroll
    for (int i = 0; i < 8; ++i) v[i] = (bf16_t)0.0f;
    return v;
}

// ---------------------------------------------------------------------------
// prep5 = prep4 (proven r6-r9) + out zeroing (needed by atomic epilogue):
//  blocks [0,256):    LDS-tiled transpose W2[k][n] -> W2t[n][k] bf16
//  blocks [256,288):  zb[m][0..8)=cos(theta[q])*cos(x[m,q]) (RX collapse:
//                     |a2|^2-|b2|^2 = cos(theta)*cos(x)); zb[m][8]=1; rest 0
//  blocks [288,296):  W1p: permuted W1 rows + bias so h-MFMA C-output lands
//                     exactly in main-MFMA A-fragment layout.
//                     Row d=(c*2+p)*16+rr holds f = c*32+(rr>>2)*8+p*4+(rr&3).
//  blocks [296,2344): out = 0  (16 MB, float4 stores)
// ---------------------------------------------------------------------------
__global__ __launch_bounds__(256)
void prep5_kernel(const float* __restrict__ x,
                  const float* __restrict__ theta,
                  const float* __restrict__ W1,
                  const float* __restrict__ b1,
                  const float* __restrict__ W2,
                  bf16_t* __restrict__ W2t,
                  bf16_t* __restrict__ zb,
                  bf16_t* __restrict__ W1p,
                  float* __restrict__ out)
{
    const int b = blockIdx.x;
    if (b >= 296) {
        // zero out[8192][512]: 2048 blocks x 256 thr x 8 floats
        float4* o4 = (float4*)out;
        int idx = ((b - 296) * 256 + (int)threadIdx.x) * 2;
        float4 z4 = {0.f, 0.f, 0.f, 0.f};
        o4[idx] = z4;
        o4[idx + 1] = z4;
        return;
    }
    if (b < 256) {
        __shared__ bf16_t T[64][66];
        const int k0 = (b >> 3) * 64;
        const int n0 = (b & 7) * 64;
        const int kl = threadIdx.x >> 4;
        const int n4 = threadIdx.x & 15;
#pragma unroll
        for (int i = 0; i < 4; ++i) {
            int k = kl + i * 16;
            float4 v = *(const float4*)(W2 + (size_t)(k0 + k) * N_TOT + n0 + n4 * 4);
            T[n4 * 4 + 0][k] = (bf16_t)v.x;
            T[n4 * 4 + 1][k] = (bf16_t)v.y;
            T[n4 * 4 + 2][k] = (bf16_t)v.z;
            T[n4 * 4 + 3][k] = (bf16_t)v.w;
        }
        __syncthreads();
        const int nl = threadIdx.x >> 4;
        const int k4 = threadIdx.x & 15;
#pragma unroll
        for (int i = 0; i < 4; ++i) {
            int n = nl + i * 16;
            bf16x4 v;
            v[0] = T[n][k4 * 4 + 0];
            v[1] = T[n][k4 * 4 + 1];
            v[2] = T[n][k4 * 4 + 2];
            v[3] = T[n][k4 * 4 + 3];
            *(bf16x4*)(W2t + (size_t)(n0 + n) * K_TOT + k0 + k4 * 4) = v;
        }
    } else if (b < 288) {
        const int m = (b - 256) * 256 + threadIdx.x;
        float4 x0 = *(const float4*)(x + (size_t)m * E_TOT);
        float4 x1 = *(const float4*)(x + (size_t)m * E_TOT + 4);
        float xs[8] = {x0.x, x0.y, x0.z, x0.w, x1.x, x1.y, x1.z, x1.w};
        bf16x8 lo;
#pragma unroll
        for (int q = 0; q < 8; ++q)
            lo[q] = (bf16_t)(__builtin_cosf(theta[q]) * __builtin_cosf(xs[q]));
        bf16x8 hi = zero8();
        hi[0] = (bf16_t)1.0f;                  // bias lane at k=8
        *(bf16x8*)(zb + (size_t)m * 16)     = lo;
        *(bf16x8*)(zb + (size_t)m * 16 + 8) = hi;
    } else {
        const int d  = (b - 288) * 256 + threadIdx.x;    // 0..2047
        const int c  = d >> 5;
        const int dd = d & 31;
        const int p  = dd >> 4;
        const int rr = dd & 15;
        const int f  = c * 32 + ((rr >> 2) << 3) + (p << 2) + (rr & 3);
        bf16x8 lo;
#pragma unroll
        for (int q = 0; q < 8; ++q)
            lo[q] = (bf16_t)W1[(size_t)q * K_TOT + f];
        bf16x8 hi = zero8();
        hi[0] = (bf16_t)b1[f];                 // bias at k=8
        *(bf16x8*)(W1p + (size_t)d * 16)     = lo;
        *(bf16x8*)(W1p + (size_t)d * 16 + 8) = hi;
    }
}

// ---------------------------------------------------------------------------
// helpers — byte-identical to r7 (best measured gemm structure)
// ---------------------------------------------------------------------------
__device__ __forceinline__ void load_B(const bf16_t* __restrict__ W2t, int n_base,
                                       int k0, int t, uint4 gv[4]) {
#pragma unroll
    for (int j = 0; j < 4; ++j) {
        int s    = t + j * 256;        // 0..1023
        int tile = s >> 9;             // 0..1
        int n    = (s >> 3) & 63;
        int g    = (s & 7) ^ (n & 7);
        gv[j] = *(const uint4*)(W2t + (size_t)(n_base + n) * K_TOT
                                + k0 + tile * 64 + g * 8);
    }
}
__device__ __forceinline__ void write_B(bf16_t* Bb, int t, const uint4 gv[4]) {
#pragma unroll
    for (int j = 0; j < 4; ++j) {
        int s    = t + j * 256;
        int tile = s >> 9;
        int n    = (s >> 3) & 63;
        int seg  = s & 7;
        *(uint4*)(Bb + tile * 4096 + n * 64 + seg * 8) = gv[j];
    }
}

__device__ __forceinline__ void load_wf(const bf16_t* __restrict__ W1p, int k0,
                                        int l15, int lq, bf16x8 wf[4]) {
#pragma unroll
    for (int i = 0; i < 4; ++i) wf[i] = zero8();
    if (lq < 2) {
        const int base = (k0 >> 5) * 2;
#pragma unroll
        for (int i = 0; i < 4; ++i)
            wf[i] = *(const bf16x8*)(W1p + (size_t)((base + i) * 16 + l15) * 16 + lq * 8);
    }
}

// one 64-k tile: B frags from LDS, h in registers (layout-matched MFMA), mains.
__device__ __forceinline__ void compute_tile(const bf16_t* Bb, const bf16x8 wf[4],
                                             const bf16x8 zfrag[2],
                                             int l15, int lq,
                                             f32x4 acc[2][4]) {
    bf16x8 bfr[2][4];
#pragma unroll
    for (int c = 0; c < 2; ++c)
#pragma unroll
        for (int nt = 0; nt < 4; ++nt) {
            int r = nt * 16 + l15;
            int s = (c * 4 + lq) ^ (r & 7);
            bfr[c][nt] = *(const bf16x8*)(Bb + r * 64 + s * 8);
        }

    bf16x8 af[2][2];
#pragma unroll
    for (int mt = 0; mt < 2; ++mt)
#pragma unroll
        for (int c = 0; c < 2; ++c) {
            f32x4 h0 = (f32x4){0.f, 0.f, 0.f, 0.f};
            f32x4 h1 = (f32x4){0.f, 0.f, 0.f, 0.f};
            h0 = __builtin_amdgcn_mfma_f32_16x16x32_bf16(wf[c * 2 + 0], zfrag[mt], h0, 0, 0, 0);
            h1 = __builtin_amdgcn_mfma_f32_16x16x32_bf16(wf[c * 2 + 1], zfrag[mt], h1, 0, 0, 0);
            bf16x8 a;
#pragma unroll
            for (int r = 0; r < 4; ++r) {
                a[r]     = (bf16_t)fmaxf(h0[r], 0.f);
                a[r + 4] = (bf16_t)fmaxf(h1[r], 0.f);
            }
            af[mt][c] = a;
        }

#pragma unroll
    for (int c = 0; c < 2; ++c)
#pragma unroll
        for (int mt = 0; mt < 2; ++mt)
#pragma unroll
            for (int nt = 0; nt < 4; ++nt)
                acc[mt][nt] = __builtin_amdgcn_mfma_f32_16x16x32_bf16(
                    af[mt][c], bfr[c][nt], acc[mt][nt], 0, 0, 0);
}

// ---------------------------------------------------------------------------
// Fused GEMM, r7 structure + K-SPLIT 2 for occupancy:
// Block 128m x 64n x (K/2), 256 thr = 4 waves m-split (wave 32m x 64n).
// Grid (8,64,2) = 1024 blocks = 4 blocks/CU = 16 waves/CU = 4 waves/SIMD —
// double r7's latency hiding; per-CU LDS/MFMA/VALU totals unchanged.
// BK=128 dbuf (2x16KB LDS), ONE barrier per segment, 8 segments per block.
// Epilogue: unsafeAtomicAdd f32 (out pre-zeroed in prep5); kk==0 adds bias.
// ---------------------------------------------------------------------------
__global__ __launch_bounds__(256, 4)
void ffq_gemm_kernel(const bf16_t* __restrict__ zb,    // [8192][16]
                     const bf16_t* __restrict__ W1p,   // [2048][16] permuted
                     const bf16_t* __restrict__ W2t,   // [512][2048]
                     const float* __restrict__ b2,
                     float* __restrict__ out)          // [8192][512] (zeroed)
{
    __shared__ bf16_t Blds[2][2 * 64 * 64];   // 2 bufs x (two 64x64 k-tiles)

    const int t = threadIdx.x;
    const int w = t >> 6, l = t & 63;
    const int m_base = blockIdx.y * 128;
    const int n_base = blockIdx.x * 64;
    const int kk     = blockIdx.z;             // k-half
    const int kbase  = kk * (K_TOT / 2);       // 0 or 1024
    const int wm = w;                          // 4 m-slots of 32
    const int l15 = l & 15, lq = l >> 4;

    // persistent z^T B-frags for this wave's two 16-row m-tiles
    bf16x8 zfrag[2];
#pragma unroll
    for (int mt = 0; mt < 2; ++mt) {
        zfrag[mt] = zero8();
        if (lq < 2)
            zfrag[mt] = *(const bf16x8*)(zb + (size_t)(m_base + wm * 32 + mt * 16 + l15) * 16 + lq * 8);
    }

    f32x4 acc[2][4];
#pragma unroll
    for (int mt = 0; mt < 2; ++mt)
#pragma unroll
        for (int nt = 0; nt < 4; ++nt)
            acc[mt][nt] = (f32x4){0.f, 0.f, 0.f, 0.f};

    uint4 gv[4];

    // prologue: first segment of this k-half -> buf0
    load_B(W2t, n_base, kbase, t, gv);
    write_B(Blds[0], t, gv);

    for (int s = 0; s < NSEG_HALF; ++s) {
        const int cur = s & 1;
        __syncthreads();                               // publish buf[cur]
        if (s + 1 < NSEG_HALF) load_B(W2t, n_base, kbase + (s + 1) * 128, t, gv);

#pragma unroll
        for (int tt = 0; tt < 2; ++tt) {
            bf16x8 wf[4];
            load_wf(W1p, kbase + s * 128 + tt * 64, l15, lq, wf);
            compute_tile(Blds[cur] + tt * 4096, wf, zfrag, l15, lq, acc);
        }

        if (s + 1 < NSEG_HALF) write_B(Blds[1 - cur], t, gv);   // precise vmcnt
    }

    // ---- epilogue: C/D layout col=lane&15, row=(lane>>4)*4+r; atomic add ----
#pragma unroll
    for (int nt = 0; nt < 4; ++nt) {
        int col = n_base + nt * 16 + l15;
        float bias = (kk == 0) ? b2[col] : 0.0f;
#pragma unroll
        for (int mt = 0; mt < 2; ++mt) {
#pragma unroll
            for (int r = 0; r < 4; ++r) {
                int row = m_base + wm * 32 + mt * 16 + lq * 4 + r;
                unsafeAtomicAdd(&out[(size_t)row * N_TOT + col],
                                acc[mt][nt][r] + bias);
            }
        }
    }
}

extern "C" void kernel_launch(void* const* d_in, const int* in_sizes, int n_in,
                              void* d_out, int out_size, void* d_ws, size_t ws_size,
                              hipStream_t stream) {
    const float* x     = (const float*)d_in[0];
    const float* theta = (const float*)d_in[1];
    const float* W1    = (const float*)d_in[2];
    const float* b1    = (const float*)d_in[3];
    const float* W2    = (const float*)d_in[4];
    const float* b2    = (const float*)d_in[5];
    float* out = (float*)d_out;

    // ws: [0,2MB) W2t ; [2MB,2.25MB) zb[8192][16] ; then W1p[2048][16]
    const size_t W2T_BYTES = (size_t)N_TOT * K_TOT * sizeof(bf16_t);  // 2 MB
    const size_t ZB_BYTES  = (size_t)M_TOT * 16 * sizeof(bf16_t);     // 256 KB

    bf16_t* W2t = (bf16_t*)d_ws;
    bf16_t* zb  = (bf16_t*)((char*)d_ws + W2T_BYTES);
    bf16_t* W1p = (bf16_t*)((char*)d_ws + W2T_BYTES + ZB_BYTES);

    // prep + out zeroing (296 prep blocks + 2048 zero blocks)
    prep5_kernel<<<2344, 256, 0, stream>>>(x, theta, W1, b1, W2, W2t, zb, W1p, out);

    dim3 grid(N_TOT / 64, M_TOT / 128, 2);   // (8, 64, 2) = 1024 blocks, 4/CU
    ffq_gemm_kernel<<<grid, 256, 0, stream>>>(zb, W1p, W2t, b2, out);
}

// Round 11
// 118.544 us; speedup vs baseline: 1.0505x; 1.0113x over previous
//
#include <hip/hip_runtime.h>
#include <hip/hip_bf16.h>

typedef __bf16 bf16_t;
typedef __bf16 bf16x4 __attribute__((ext_vector_type(4)));
typedef __bf16 bf16x8 __attribute__((ext_vector_type(8)));
typedef float f32x4 __attribute__((ext_vector_type(4)));

#define M_TOT 8192
#define N_TOT 512
#define K_TOT 2048
#define E_TOT 512

__device__ __forceinline__ bf16x8 zero8() {
    bf16x8 v;
#pragma unroll
    for (int i = 0; i < 8; ++i) v[i] = (bf16_t)0.0f;
    return v;
}

// ---------------------------------------------------------------------------
// prep4 (unchanged; correctness-proven r6-r10):
//  blocks [0,256):   LDS-tiled transpose W2[k][n] -> W2t[n][k] bf16
//  blocks [256,288): zb[m][0..8)=cos(theta[q])*cos(x[m,q]) (RX collapse:
//                    |a2|^2-|b2|^2 = cos(theta)*cos(x)); zb[m][8]=1; rest 0
//  blocks [288,296): W1p: permuted W1 rows + bias so h-MFMA C-output lands
//                    exactly in main-MFMA A-fragment layout.
//                    Row d=(c*2+p)*16+rr holds f = c*32+(rr>>2)*8+p*4+(rr&3).
// ---------------------------------------------------------------------------
__global__ __launch_bounds__(256)
void prep4_kernel(const float* __restrict__ x,
                  const float* __restrict__ theta,
                  const float* __restrict__ W1,
                  const float* __restrict__ b1,
                  const float* __restrict__ W2,
                  bf16_t* __restrict__ W2t,
                  bf16_t* __restrict__ zb,
                  bf16_t* __restrict__ W1p)
{
    const int b = blockIdx.x;
    if (b < 256) {
        __shared__ bf16_t T[64][66];
        const int k0 = (b >> 3) * 64;
        const int n0 = (b & 7) * 64;
        const int kl = threadIdx.x >> 4;
        const int n4 = threadIdx.x & 15;
#pragma unroll
        for (int i = 0; i < 4; ++i) {
            int k = kl + i * 16;
            float4 v = *(const float4*)(W2 + (size_t)(k0 + k) * N_TOT + n0 + n4 * 4);
            T[n4 * 4 + 0][k] = (bf16_t)v.x;
            T[n4 * 4 + 1][k] = (bf16_t)v.y;
            T[n4 * 4 + 2][k] = (bf16_t)v.z;
            T[n4 * 4 + 3][k] = (bf16_t)v.w;
        }
        __syncthreads();
        const int nl = threadIdx.x >> 4;
        const int k4 = threadIdx.x & 15;
#pragma unroll
        for (int i = 0; i < 4; ++i) {
            int n = nl + i * 16;
            bf16x4 v;
            v[0] = T[n][k4 * 4 + 0];
            v[1] = T[n][k4 * 4 + 1];
            v[2] = T[n][k4 * 4 + 2];
            v[3] = T[n][k4 * 4 + 3];
            *(bf16x4*)(W2t + (size_t)(n0 + n) * K_TOT + k0 + k4 * 4) = v;
        }
    } else if (b < 288) {
        const int m = (b - 256) * 256 + threadIdx.x;
        float4 x0 = *(const float4*)(x + (size_t)m * E_TOT);
        float4 x1 = *(const float4*)(x + (size_t)m * E_TOT + 4);
        float xs[8] = {x0.x, x0.y, x0.z, x0.w, x1.x, x1.y, x1.z, x1.w};
        bf16x8 lo;
#pragma unroll
        for (int q = 0; q < 8; ++q)
            lo[q] = (bf16_t)(__builtin_cosf(theta[q]) * __builtin_cosf(xs[q]));
        bf16x8 hi = zero8();
        hi[0] = (bf16_t)1.0f;                  // bias lane at k=8
        *(bf16x8*)(zb + (size_t)m * 16)     = lo;
        *(bf16x8*)(zb + (size_t)m * 16 + 8) = hi;
    } else {
        const int d  = (b - 288) * 256 + threadIdx.x;    // 0..2047
        const int c  = d >> 5;
        const int dd = d & 31;
        const int p  = dd >> 4;
        const int rr = dd & 15;
        const int f  = c * 32 + ((rr >> 2) << 3) + (p << 2) + (rr & 3);
        bf16x8 lo;
#pragma unroll
        for (int q = 0; q < 8; ++q)
            lo[q] = (bf16_t)W1[(size_t)q * K_TOT + f];
        bf16x8 hi = zero8();
        hi[0] = (bf16_t)b1[f];                 // bias at k=8
        *(bf16x8*)(W1p + (size_t)d * 16)     = lo;
        *(bf16x8*)(W1p + (size_t)d * 16 + 8) = hi;
    }
}

// ---------------------------------------------------------------------------
// LDS-free helpers: B-fragments straight from global (W2t k-contiguous rows,
// L1/L2-resident). One global_load_dwordx4 per fragment, NO swizzle needed.
// ---------------------------------------------------------------------------
__device__ __forceinline__ void load_bfr(const bf16_t* __restrict__ W2t, int n_base,
                                         int k0, int l15, int lq, bf16x8 bfr[8]) {
#pragma unroll
    for (int c = 0; c < 2; ++c)
#pragma unroll
        for (int nt = 0; nt < 4; ++nt)
            bfr[c * 4 + nt] = *(const bf16x8*)(W2t
                + (size_t)(n_base + nt * 16 + l15) * K_TOT + k0 + (c * 4 + lq) * 8);
}

// W1p frags for one 64k tile (2 chunks x 2 perm-halves); lanes lq<2 real.
__device__ __forceinline__ void load_wf(const bf16_t* __restrict__ W1p, int k0,
                                        int l15, int lq, bf16x8 wf[4]) {
#pragma unroll
    for (int i = 0; i < 4; ++i) wf[i] = zero8();
    if (lq < 2) {
        const int base = (k0 >> 5) * 2;
#pragma unroll
        for (int i = 0; i < 4; ++i)
            wf[i] = *(const bf16x8*)(W1p + (size_t)((base + i) * 16 + l15) * 16 + lq * 8);
    }
}

// one 64k tile: h in registers (layout-matched h-MFMA), then 32 main MFMAs.
__device__ __forceinline__ void compute64(const bf16x8 bfr[8], const bf16x8 wf[4],
                                          const bf16x8 zfrag[4], f32x4 acc[4][4]) {
    bf16x8 af[4][2];
#pragma unroll
    for (int mt = 0; mt < 4; ++mt)
#pragma unroll
        for (int c = 0; c < 2; ++c) {
            f32x4 h0 = (f32x4){0.f, 0.f, 0.f, 0.f};
            f32x4 h1 = (f32x4){0.f, 0.f, 0.f, 0.f};
            h0 = __builtin_amdgcn_mfma_f32_16x16x32_bf16(wf[c * 2 + 0], zfrag[mt], h0, 0, 0, 0);
            h1 = __builtin_amdgcn_mfma_f32_16x16x32_bf16(wf[c * 2 + 1], zfrag[mt], h1, 0, 0, 0);
            bf16x8 a;
#pragma unroll
            for (int r = 0; r < 4; ++r) {
                a[r]     = (bf16_t)fmaxf(h0[r], 0.f);
                a[r + 4] = (bf16_t)fmaxf(h1[r], 0.f);
            }
            af[mt][c] = a;
        }
#pragma unroll
    for (int c = 0; c < 2; ++c)
#pragma unroll
        for (int mt = 0; mt < 4; ++mt)
#pragma unroll
            for (int nt = 0; nt < 4; ++nt)
                acc[mt][nt] = __builtin_amdgcn_mfma_f32_16x16x32_bf16(
                    af[mt][c], bfr[c * 4 + nt], acc[mt][nt], 0, 0, 0);
}

// ---------------------------------------------------------------------------
// Fused GEMM, BARRIER-FREE K-loop: out = relu(z@W1+b1) @ W2 + b2
// Block 512 thr = 8 waves = 4 m-slots x 2 k-halves; wave tile 64m x 64n over
// 1024 k. Grid (8,32) = 256 blocks = 1/CU = 8 waves/CU (2/SIMD).
// No LDS staging, no barriers in the loop: B-frags read directly from
// global (W2t 2MB = L2-resident per XCD; block's 4 m-waves share via L1),
// ping-pong double-buffered in registers. h via layout-matched h-MFMA.
// Single __syncthreads at the end for the k-half LDS reduction.
// ---------------------------------------------------------------------------
__global__ __launch_bounds__(512, 2)
void ffq_gemm_kernel(const bf16_t* __restrict__ zb,    // [8192][16]
                     const bf16_t* __restrict__ W1p,   // [2048][16] permuted
                     const bf16_t* __restrict__ W2t,   // [512][2048]
                     const float* __restrict__ b2,
                     float* __restrict__ out)          // [8192][512]
{
    __shared__ float Red[4][64 * 64];   // 64 KB k-half reduction scratch

    const int t = threadIdx.x;
    const int w = t >> 6, l = t & 63;
    const int wm = w & 3, wk = w >> 2;            // m-slot, k-half
    const int m_base = blockIdx.y * 256 + wm * 64;
    const int n_base = blockIdx.x * 64;
    const int l15 = l & 15, lq = l >> 4;
    const int kbase = wk * (K_TOT / 2);           // 0 or 1024

    // persistent z^T B-frags for this wave's four 16-row m-tiles
    bf16x8 zfrag[4];
#pragma unroll
    for (int mt = 0; mt < 4; ++mt) {
        zfrag[mt] = zero8();
        if (lq < 2)
            zfrag[mt] = *(const bf16x8*)(zb + (size_t)(m_base + mt * 16 + l15) * 16 + lq * 8);
    }

    f32x4 acc[4][4];
#pragma unroll
    for (int mt = 0; mt < 4; ++mt)
#pragma unroll
        for (int nt = 0; nt < 4; ++nt)
            acc[mt][nt] = (f32x4){0.f, 0.f, 0.f, 0.f};

    bf16x8 bfrA[8], bfrB[8], wfA[4], wfB[4];

    // prologue: tile 0 of this k-half
    load_bfr(W2t, n_base, kbase, l15, lq, bfrA);
    load_wf(W1p, kbase, l15, lq, wfA);

    for (int kt = 0; kt < 16; kt += 2) {
        const int k0 = kbase + kt * 64;
        // prefetch kt+1 (in flight across compute of kt)
        load_bfr(W2t, n_base, k0 + 64, l15, lq, bfrB);
        load_wf(W1p, k0 + 64, l15, lq, wfB);
        compute64(bfrA, wfA, zfrag, acc);

        // prefetch kt+2; compute kt+1
        if (kt + 2 < 16) {
            load_bfr(W2t, n_base, k0 + 128, l15, lq, bfrA);
            load_wf(W1p, k0 + 128, l15, lq, wfA);
        }
        compute64(bfrB, wfB, zfrag, acc);
    }

    // ---- k-half reduction through LDS (the ONLY barrier) ----
    if (wk == 1) {
#pragma unroll
        for (int mt = 0; mt < 4; ++mt)
#pragma unroll
            for (int nt = 0; nt < 4; ++nt)
#pragma unroll
                for (int r = 0; r < 4; ++r)
                    Red[wm][(mt * 16 + lq * 4 + r) * 64 + nt * 16 + l15] = acc[mt][nt][r];
    }
    __syncthreads();
    if (wk == 0) {
#pragma unroll
        for (int nt = 0; nt < 4; ++nt) {
            int col = n_base + nt * 16 + l15;
            float bias = b2[col];
#pragma unroll
            for (int mt = 0; mt < 4; ++mt) {
#pragma unroll
                for (int r = 0; r < 4; ++r) {
                    int row = m_base + mt * 16 + lq * 4 + r;
                    out[(size_t)row * N_TOT + col] = acc[mt][nt][r] + bias
                        + Red[wm][(mt * 16 + lq * 4 + r) * 64 + nt * 16 + l15];
                }
            }
        }
    }
}

extern "C" void kernel_launch(void* const* d_in, const int* in_sizes, int n_in,
                              void* d_out, int out_size, void* d_ws, size_t ws_size,
                              hipStream_t stream) {
    const float* x     = (const float*)d_in[0];
    const float* theta = (const float*)d_in[1];
    const float* W1    = (const float*)d_in[2];
    const float* b1    = (const float*)d_in[3];
    const float* W2    = (const float*)d_in[4];
    const float* b2    = (const float*)d_in[5];
    float* out = (float*)d_out;

    // ws: [0,2MB) W2t ; [2MB,2.25MB) zb[8192][16] ; then W1p[2048][16]
    const size_t W2T_BYTES = (size_t)N_TOT * K_TOT * sizeof(bf16_t);  // 2 MB
    const size_t ZB_BYTES  = (size_t)M_TOT * 16 * sizeof(bf16_t);     // 256 KB

    bf16_t* W2t = (bf16_t*)d_ws;
    bf16_t* zb  = (bf16_t*)((char*)d_ws + W2T_BYTES);
    bf16_t* W1p = (bf16_t*)((char*)d_ws + W2T_BYTES + ZB_BYTES);

    prep4_kernel<<<296, 256, 0, stream>>>(x, theta, W1, b1, W2, W2t, zb, W1p);

    dim3 grid(N_TOT / 64, M_TOT / 256);   // (8, 32) = 256 blocks, 1/CU
    ffq_gemm_kernel<<<grid, 512, 0, stream>>>(zb, W1p, W2t, b2, out);
}